// Round 22
// baseline (127.636 us; speedup 1.0000x reference)
//
#include <hip/hip_runtime.h>
#include <hip/hip_bf16.h>

// NAM_89739046683406: per-feature tiny MLP (B=32768, F=128, H=64)
// logit(b) = bias + sum_f [ relu(relu(x[b,f]*w1[f]+b1[f]) @ w2[f] + b2[f]) . w3[f] + b3[f] ]
// out = [1-sigmoid, sigmoid]
//
// R22 = R21 (fused prep, 2 dispatches, main 62us) + packed-f32 math done
// SAFELY: v_pk_fma_f32/v_pk_max_f32 via arithmetic on NAMED float2v SSA
// variables only. Forensics across R16-R21: scratch demotion (FETCH/WRITE
// blowup at low VGPR_Count) is triggered specifically by ARRAYS of float2v
// (R17/R18: wk2[2][4]/w3p[4][2]/s2[4] -> 374MB FETCH); plain-float arrays and
// short8/floatx4 arrays are always clean. So: 16 named wk/bk pairs, 8 named
// w3 pairs, 4 named s2 accumulators, compile-time-indexed macros.
// Saves ~128 VALU/chunk (h1 160->96, epilogue 128->64).
//
// Hard constraints:
//   - LB must be (256,3); (256,4) demotes (R13-R15).
//   - NO arrays of float2v (R17/R18); named SSA float2v only.
//   - Judge spills by FETCH/WRITE counters, not VGPR_Count.

#define B_SZ 32768
#define F_SZ 128
#define H_SZ 64

typedef short short8 __attribute__((ext_vector_type(8)));   // bf16 x8
typedef float floatx4 __attribute__((ext_vector_type(4)));  // fp32 x4 acc
typedef float float2v __attribute__((ext_vector_type(2)));  // fp32 x2 (pk ops)

// round-half-up bf16 pair-pack (proven form)
__device__ __forceinline__ unsigned pkbf(float lo, float hi) {
    unsigned ua = __float_as_uint(lo) + 0x8000u;
    unsigned ub = __float_as_uint(hi) + 0x8000u;
    return (ua >> 16) | (ub & 0xFFFF0000u);
}

// ---- main: block = 4 waves; wave wv owns feature f = (bx>>6)*4+wv,
//      rows [rg*512, rg*512+512), rg = bx&63. 8 chunks of 64 rows.
//      Preamble packs w2[f] -> A-fragments in registers (no prep kernel).
//      Output: part[gf][rb..rb+512) plain store (sole writer).
__global__ __launch_bounds__(256, 3)
void nam_main(const float* __restrict__ x,
              const float* __restrict__ w1, const float* __restrict__ b1,
              const float* __restrict__ b2, const float* __restrict__ w3,
              const float* __restrict__ b3,
              const float* __restrict__ w2,
              float* __restrict__ part)
{
    __shared__ float partial[4][512];    // 8KB

    const int tid  = threadIdx.x;
    const int lane = tid & 63;
    const int wv   = tid >> 6;           // 0..3
    const int l15  = lane & 15;
    const int quad = lane >> 4;
    const int rg   = blockIdx.x & 63;
    const int gf   = blockIdx.x >> 6;    // 0..31
    const int f    = gf * 4 + wv;
    const int rb   = rg * 512;

    // ---- per-wave resident tables ----
    // w2 A-fragments packed in-place from fp32 source:
    // frag (gt,ks): elem j = w2[f][k=ks*32+quad*8+j][g=gt*16+l15]
    const float* w2f = w2 + (size_t)f * H_SZ * H_SZ;
    short8 wfrag[4][2];
    #pragma unroll
    for (int gt = 0; gt < 4; ++gt)
        #pragma unroll
        for (int ks = 0; ks < 2; ++ks) {
            const float* src = w2f + (ks * 32 + quad * 8) * H_SZ + gt * 16 + l15;
            union { short8 s8; unsigned u[4]; } o;
            #pragma unroll
            for (int t = 0; t < 4; ++t)
                o.u[t] = pkbf(src[(2 * t) * H_SZ], src[(2 * t + 1) * H_SZ]);
            wfrag[gt][ks] = o.s8;
        }

    // w1/b1 as NAMED float2v pairs (k = ks*32 + quad*8 + {2t,2t+1})
    float2v wk0a, wk0b, wk0c, wk0d, bk0a, bk0b, bk0c, bk0d;
    float2v wk1a, wk1b, wk1c, wk1d, bk1a, bk1b, bk1c, bk1d;
    {
        float4 a0 = *(const float4*)(w1 + f * 64 + quad * 8);
        float4 a1 = *(const float4*)(w1 + f * 64 + quad * 8 + 4);
        float4 a2 = *(const float4*)(w1 + f * 64 + 32 + quad * 8);
        float4 a3 = *(const float4*)(w1 + f * 64 + 32 + quad * 8 + 4);
        wk0a = float2v{a0.x, a0.y}; wk0b = float2v{a0.z, a0.w};
        wk0c = float2v{a1.x, a1.y}; wk0d = float2v{a1.z, a1.w};
        wk1a = float2v{a2.x, a2.y}; wk1b = float2v{a2.z, a2.w};
        wk1c = float2v{a3.x, a3.y}; wk1d = float2v{a3.z, a3.w};
        float4 c0 = *(const float4*)(b1 + f * 64 + quad * 8);
        float4 c1 = *(const float4*)(b1 + f * 64 + quad * 8 + 4);
        float4 c2 = *(const float4*)(b1 + f * 64 + 32 + quad * 8);
        float4 c3 = *(const float4*)(b1 + f * 64 + 32 + quad * 8 + 4);
        bk0a = float2v{c0.x, c0.y}; bk0b = float2v{c0.z, c0.w};
        bk0c = float2v{c1.x, c1.y}; bk0d = float2v{c1.z, c1.w};
        bk1a = float2v{c2.x, c2.y}; bk1b = float2v{c2.z, c2.w};
        bk1c = float2v{c3.x, c3.y}; bk1d = float2v{c3.z, c3.w};
    }

    // b2 as MFMA C quads (floatx4 array: proven clean R20/R21)
    floatx4 b2c[4];
    // w3 as NAMED float2v pairs (g = gt*16 + quad*4 + {0,1},{2,3})
    float2v w3_0a, w3_0b, w3_1a, w3_1b, w3_2a, w3_2b, w3_3a, w3_3b;
    #pragma unroll
    for (int gt = 0; gt < 4; ++gt) {
        float4 bv = *(const float4*)(b2 + f * 64 + gt * 16 + quad * 4);
        b2c[gt] = floatx4{bv.x, bv.y, bv.z, bv.w};
    }
    {
        float4 v0 = *(const float4*)(w3 + f * 64 + 0 * 16 + quad * 4);
        float4 v1 = *(const float4*)(w3 + f * 64 + 1 * 16 + quad * 4);
        float4 v2 = *(const float4*)(w3 + f * 64 + 2 * 16 + quad * 4);
        float4 v3 = *(const float4*)(w3 + f * 64 + 3 * 16 + quad * 4);
        w3_0a = float2v{v0.x, v0.y}; w3_0b = float2v{v0.z, v0.w};
        w3_1a = float2v{v1.x, v1.y}; w3_1b = float2v{v1.z, v1.w};
        w3_2a = float2v{v2.x, v2.y}; w3_2b = float2v{v2.z, v2.w};
        w3_3a = float2v{v3.x, v3.y}; w3_3b = float2v{v3.z, v3.w};
    }
    const float b3f = b3[f];
    const float2v zero2 = float2v{0.0f, 0.0f};

    // ---- 8 chunks of 64 rows, software-pipelined x gather ----
    float xv = x[(size_t)(rb + lane) * F_SZ + f];   // chunk 0

#define MK_HF(BT, KS, WA, WB, WC, WD, BA, BB, BC, BD) do {                \
        float2v xb = float2v{xf[BT], xf[BT]};                             \
        float2v h0 = __builtin_elementwise_max(xb * WA + BA, zero2);      \
        float2v h1 = __builtin_elementwise_max(xb * WB + BB, zero2);      \
        float2v h2 = __builtin_elementwise_max(xb * WC + BC, zero2);      \
        float2v h3 = __builtin_elementwise_max(xb * WD + BD, zero2);      \
        union { short8 s8; __hip_bfloat162 q[4]; } o;                     \
        o.q[0] = __float22bfloat162_rn(make_float2(h0.x, h0.y));          \
        o.q[1] = __float22bfloat162_rn(make_float2(h1.x, h1.y));          \
        o.q[2] = __float22bfloat162_rn(make_float2(h2.x, h2.y));          \
        o.q[3] = __float22bfloat162_rn(make_float2(h3.x, h3.y));          \
        hfrag[BT][KS] = o.s8;                                             \
    } while (0)

#define EPI(GT, BT, W3A, W3B, S2) do {                                    \
        floatx4 acc = __builtin_amdgcn_mfma_f32_16x16x32_bf16(            \
            wfrag[GT][0], hfrag[BT][0], b2c[GT], 0, 0, 0);                \
        acc = __builtin_amdgcn_mfma_f32_16x16x32_bf16(                    \
            wfrag[GT][1], hfrag[BT][1], acc, 0, 0, 0);                    \
        float2v a01 = float2v{acc[0], acc[1]};                            \
        float2v a23 = float2v{acc[2], acc[3]};                            \
        S2 = __builtin_elementwise_max(a01, zero2) * W3A + S2;            \
        S2 = __builtin_elementwise_max(a23, zero2) * W3B + S2;            \
    } while (0)

    #pragma unroll 1
    for (int c = 0; c < 8; ++c) {
        float xvn;
        if (c < 7)
            xvn = x[(size_t)(rb + (c + 1) * 64 + lane) * F_SZ + f];

        float xf[4];
        #pragma unroll
        for (int bt = 0; bt < 4; ++bt)
            xf[bt] = __shfl(xv, bt * 16 + l15, 64);

        // h1 B-fragments: B[k=quad*8+j][n=bt*16+l15] (packed pk_fma/pk_max)
        short8 hfrag[4][2];
        MK_HF(0, 0, wk0a, wk0b, wk0c, wk0d, bk0a, bk0b, bk0c, bk0d);
        MK_HF(0, 1, wk1a, wk1b, wk1c, wk1d, bk1a, bk1b, bk1c, bk1d);
        MK_HF(1, 0, wk0a, wk0b, wk0c, wk0d, bk0a, bk0b, bk0c, bk0d);
        MK_HF(1, 1, wk1a, wk1b, wk1c, wk1d, bk1a, bk1b, bk1c, bk1d);
        MK_HF(2, 0, wk0a, wk0b, wk0c, wk0d, bk0a, bk0b, bk0c, bk0d);
        MK_HF(2, 1, wk1a, wk1b, wk1c, wk1d, bk1a, bk1b, bk1c, bk1d);
        MK_HF(3, 0, wk0a, wk0b, wk0c, wk0d, bk0a, bk0b, bk0c, bk0d);
        MK_HF(3, 1, wk1a, wk1b, wk1c, wk1d, bk1a, bk1b, bk1c, bk1d);

        // MFMA (C = b2c direct) + packed epilogue into named s2 accumulators
        float2v s2_0 = zero2, s2_1 = zero2, s2_2 = zero2, s2_3 = zero2;
        EPI(0, 0, w3_0a, w3_0b, s2_0); EPI(0, 1, w3_0a, w3_0b, s2_1);
        EPI(0, 2, w3_0a, w3_0b, s2_2); EPI(0, 3, w3_0a, w3_0b, s2_3);
        EPI(1, 0, w3_1a, w3_1b, s2_0); EPI(1, 1, w3_1a, w3_1b, s2_1);
        EPI(1, 2, w3_1a, w3_1b, s2_2); EPI(1, 3, w3_1a, w3_1b, s2_3);
        EPI(2, 0, w3_2a, w3_2b, s2_0); EPI(2, 1, w3_2a, w3_2b, s2_1);
        EPI(2, 2, w3_2a, w3_2b, s2_2); EPI(2, 3, w3_2a, w3_2b, s2_3);
        EPI(3, 0, w3_3a, w3_3b, s2_0); EPI(3, 1, w3_3a, w3_3b, s2_1);
        EPI(3, 2, w3_3a, w3_3b, s2_2); EPI(3, 3, w3_3a, w3_3b, s2_3);

        // horizontal + quad-reduce (row = bt*16 + l15), publish chunk rows
        float t0 = s2_0.x + s2_0.y, t1 = s2_1.x + s2_1.y;
        float t2 = s2_2.x + s2_2.y, t3 = s2_3.x + s2_3.y;
        t0 += __shfl_xor(t0, 16, 64); t0 += __shfl_xor(t0, 32, 64);
        t1 += __shfl_xor(t1, 16, 64); t1 += __shfl_xor(t1, 32, 64);
        t2 += __shfl_xor(t2, 16, 64); t2 += __shfl_xor(t2, 32, 64);
        t3 += __shfl_xor(t3, 16, 64); t3 += __shfl_xor(t3, 32, 64);
        if (quad == 0) {
            partial[wv][c * 64 +  0 + l15] = t0 + b3f;
            partial[wv][c * 64 + 16 + l15] = t1 + b3f;
            partial[wv][c * 64 + 32 + l15] = t2 + b3f;
            partial[wv][c * 64 + 48 + l15] = t3 + b3f;
        }

        xv = xvn;
    }
#undef MK_HF
#undef EPI

    __syncthreads();

    // block reduce over the 4 features -> plain coalesced store (sole writer)
    #pragma unroll
    for (int k = 0; k < 2; ++k) {
        int row = k * 256 + tid;
        float p = partial[0][row] + partial[1][row]
                + partial[2][row] + partial[3][row];
        part[(size_t)gf * B_SZ + rb + row] = p;
    }
}

// ---- final: 1 row/thread, sum 32 gf-partials + bias + sigmoid ----
__global__ __launch_bounds__(256)
void nam_final(const float* __restrict__ part, const float* __restrict__ bias,
               float* __restrict__ out)
{
    int b = blockIdx.x * 256 + threadIdx.x;
    float s = bias[0];
    #pragma unroll
    for (int gf = 0; gf < 32; ++gf)
        s += part[(size_t)gf * B_SZ + b];
    float p = 1.0f / (1.0f + __expf(-s));
    ((float2*)out)[b] = make_float2(1.0f - p, p);
}

extern "C" void kernel_launch(void* const* d_in, const int* in_sizes, int n_in,
                              void* d_out, int out_size, void* d_ws, size_t ws_size,
                              hipStream_t stream)
{
    const float* x    = (const float*)d_in[0];
    const float* w1   = (const float*)d_in[1];
    const float* b1   = (const float*)d_in[2];
    const float* w2   = (const float*)d_in[3];
    const float* b2   = (const float*)d_in[4];
    const float* w3   = (const float*)d_in[5];
    const float* b3   = (const float*)d_in[6];
    const float* bias = (const float*)d_in[7];
    float* out = (float*)d_out;

    float* part = (float*)d_ws;   // part[32][B_SZ], 4MB

    nam_main<<<dim3(2048), dim3(256), 0, stream>>>(
        x, w1, b1, b2, w3, b3, w2, part);
    nam_final<<<dim3(B_SZ / 256), dim3(256), 0, stream>>>(part, bias, out);
}

// Round 23
// 126.306 us; speedup vs baseline: 1.0105x; 1.0105x over previous
//
#include <hip/hip_runtime.h>
#include <hip/hip_bf16.h>

// NAM_89739046683406: per-feature tiny MLP (B=32768, F=128, H=64)
// logit(b) = bias + sum_f [ relu(relu(x[b,f]*w1[f]+b1[f]) @ w2[f] + b2[f]) . w3[f] + b3[f] ]
// out = [1-sigmoid, sigmoid]
//
// R23 = R21 (best: 123.9us; fused w2-pack preamble, b2-as-MFMA-C, scalar
// wk/bk math, x gather+shfl prefetch, plain stores) + ONE change: the
// per-chunk 2-step quad butterfly (8 dependent ds_bpermute/chunk) is removed.
// Every lane stores its quad-partial t[bt] to a per-(wave,quad) LDS slice
// p2[16][520] (stride-520 pad -> 2-way banks = free); quad-sum happens once
// in the block epilogue. R22 proved the kernel is dependency-latency-bound
// (fewer instructions -> VALUBusy 76->61% but time UP); this removes the
// dominant in-loop latency chains instead of instructions.
//
// Hard constraints (demotion signature = FETCH/WRITE blowup at low VGPR):
//   - LB must be (256,3); (256,4) demotes (R13-R15).
//   - NO arrays of float2v + elementwise builtins (R17/R18).

#define B_SZ 32768
#define F_SZ 128
#define H_SZ 64

typedef short short8 __attribute__((ext_vector_type(8)));   // bf16 x8
typedef float floatx4 __attribute__((ext_vector_type(4)));  // fp32 x4 acc

// round-half-up bf16 pair-pack (proven form)
__device__ __forceinline__ unsigned pkbf(float lo, float hi) {
    unsigned ua = __float_as_uint(lo) + 0x8000u;
    unsigned ub = __float_as_uint(hi) + 0x8000u;
    return (ua >> 16) | (ub & 0xFFFF0000u);
}

#define P2S 520   // LDS slice stride (floats): 512 + 8 pad -> quad offsets hit
                  // distinct bank groups, 2 lanes/bank = conflict-free

// ---- main: block = 4 waves; wave wv owns feature f = (bx>>6)*4+wv,
//      rows [rg*512, rg*512+512), rg = bx&63. 8 chunks of 64 rows.
//      Preamble packs w2[f] -> A-fragments in registers (no prep kernel).
//      Output: part[gf][rb..rb+512) plain store (sole writer).
__global__ __launch_bounds__(256, 3)
void nam_main(const float* __restrict__ x,
              const float* __restrict__ w1, const float* __restrict__ b1,
              const float* __restrict__ b2, const float* __restrict__ w3,
              const float* __restrict__ b3,
              const float* __restrict__ w2,
              float* __restrict__ part)
{
    __shared__ float p2[16][P2S];        // 33.3KB: [wv*4+quad][row-in-block]

    const int tid  = threadIdx.x;
    const int lane = tid & 63;
    const int wv   = tid >> 6;           // 0..3
    const int l15  = lane & 15;
    const int quad = lane >> 4;
    const int rg   = blockIdx.x & 63;
    const int gf   = blockIdx.x >> 6;    // 0..31
    const int f    = gf * 4 + wv;
    const int rb   = rg * 512;

    // ---- per-wave resident tables ----
    // w2 A-fragments packed in-place from fp32 source:
    // frag (gt,ks): elem j = w2[f][k=ks*32+quad*8+j][g=gt*16+l15]
    const float* w2f = w2 + (size_t)f * H_SZ * H_SZ;
    short8 wfrag[4][2];
    #pragma unroll
    for (int gt = 0; gt < 4; ++gt)
        #pragma unroll
        for (int ks = 0; ks < 2; ++ks) {
            const float* src = w2f + (ks * 32 + quad * 8) * H_SZ + gt * 16 + l15;
            union { short8 s8; unsigned u[4]; } o;
            #pragma unroll
            for (int t = 0; t < 4; ++t)
                o.u[t] = pkbf(src[(2 * t) * H_SZ], src[(2 * t + 1) * H_SZ]);
            wfrag[gt][ks] = o.s8;
        }

    // w1/b1 fp32: element k = ks*32 + quad*8 + j
    float wk[2][8], bk[2][8];
    #pragma unroll
    for (int ks = 0; ks < 2; ++ks) {
        const float4* wq = (const float4*)(w1 + f * 64 + ks * 32 + quad * 8);
        const float4* bq = (const float4*)(b1 + f * 64 + ks * 32 + quad * 8);
        *(float4*)&wk[ks][0] = wq[0]; *(float4*)&wk[ks][4] = wq[1];
        *(float4*)&bk[ks][0] = bq[0]; *(float4*)&bk[ks][4] = bq[1];
    }

    // b2 as MFMA C operand quads; w3 scalar: element g = gt*16 + quad*4 + i
    floatx4 b2c[4];
    float w3f[4][4];
    #pragma unroll
    for (int gt = 0; gt < 4; ++gt) {
        float4 bv  = *(const float4*)(b2 + f * 64 + gt * 16 + quad * 4);
        float4 wv3 = *(const float4*)(w3 + f * 64 + gt * 16 + quad * 4);
        b2c[gt] = floatx4{bv.x, bv.y, bv.z, bv.w};
        w3f[gt][0] = wv3.x; w3f[gt][1] = wv3.y;
        w3f[gt][2] = wv3.z; w3f[gt][3] = wv3.w;
    }

    // ---- 8 chunks of 64 rows, software-pipelined x gather ----
    float xv = x[(size_t)(rb + lane) * F_SZ + f];   // chunk 0

    #pragma unroll 1
    for (int c = 0; c < 8; ++c) {
        float xvn;
        if (c < 7)
            xvn = x[(size_t)(rb + (c + 1) * 64 + lane) * F_SZ + f];

        float xf[4];
        #pragma unroll
        for (int bt = 0; bt < 4; ++bt)
            xf[bt] = __shfl(xv, bt * 16 + l15, 64);

        // h1 B-fragments: B[k=quad*8+j][n=bt*16+l15]
        short8 hfrag[4][2];
        #pragma unroll
        for (int ks = 0; ks < 2; ++ks)
            #pragma unroll
            for (int bt = 0; bt < 4; ++bt) {
                union { short8 s8; __hip_bfloat162 h2[4]; } o;
                #pragma unroll
                for (int t = 0; t < 4; ++t) {
                    float h0 = fmaxf(fmaf(xf[bt], wk[ks][2 * t],     bk[ks][2 * t]),     0.0f);
                    float h1 = fmaxf(fmaf(xf[bt], wk[ks][2 * t + 1], bk[ks][2 * t + 1]), 0.0f);
                    o.h2[t] = __float22bfloat162_rn(make_float2(h0, h1));
                }
                hfrag[bt][ks] = o.s8;
            }

        // MFMA (C = b2c direct, D != C) + epilogue
        // D layout: g = gt*16 + quad*4 + i, n = bt*16 + l15
        float t[4] = {0.0f, 0.0f, 0.0f, 0.0f};
        #pragma unroll
        for (int gt = 0; gt < 4; ++gt)
            #pragma unroll
            for (int bt = 0; bt < 4; ++bt) {
                floatx4 acc = __builtin_amdgcn_mfma_f32_16x16x32_bf16(
                    wfrag[gt][0], hfrag[bt][0], b2c[gt], 0, 0, 0);
                acc = __builtin_amdgcn_mfma_f32_16x16x32_bf16(
                    wfrag[gt][1], hfrag[bt][1], acc, 0, 0, 0);
                #pragma unroll
                for (int i = 0; i < 4; ++i)
                    t[bt] = fmaf(fmaxf(acc[i], 0.0f), w3f[gt][i], t[bt]);
            }

        // no butterfly: every lane stores its quad-partial (fire-and-forget)
        #pragma unroll
        for (int bt = 0; bt < 4; ++bt)
            p2[wv * 4 + quad][c * 64 + bt * 16 + l15] = t[bt];

        xv = xvn;
    }

    __syncthreads();

    // block epilogue: sum the 16 (wave,quad) slices per row + the 4 b3's,
    // plain coalesced store (sole writer)
    const float b3s = b3[gf * 4] + b3[gf * 4 + 1] + b3[gf * 4 + 2] + b3[gf * 4 + 3];
    #pragma unroll
    for (int k = 0; k < 2; ++k) {
        int row = k * 256 + tid;
        float p = b3s;
        #pragma unroll
        for (int s = 0; s < 16; ++s)
            p += p2[s][row];
        part[(size_t)gf * B_SZ + rb + row] = p;
    }
}

// ---- final: 1 row/thread, sum 32 gf-partials + bias + sigmoid ----
__global__ __launch_bounds__(256)
void nam_final(const float* __restrict__ part, const float* __restrict__ bias,
               float* __restrict__ out)
{
    int b = blockIdx.x * 256 + threadIdx.x;
    float s = bias[0];
    #pragma unroll
    for (int gf = 0; gf < 32; ++gf)
        s += part[(size_t)gf * B_SZ + b];
    float p = 1.0f / (1.0f + __expf(-s));
    ((float2*)out)[b] = make_float2(1.0f - p, p);
}

extern "C" void kernel_launch(void* const* d_in, const int* in_sizes, int n_in,
                              void* d_out, int out_size, void* d_ws, size_t ws_size,
                              hipStream_t stream)
{
    const float* x    = (const float*)d_in[0];
    const float* w1   = (const float*)d_in[1];
    const float* b1   = (const float*)d_in[2];
    const float* w2   = (const float*)d_in[3];
    const float* b2   = (const float*)d_in[4];
    const float* w3   = (const float*)d_in[5];
    const float* b3   = (const float*)d_in[6];
    const float* bias = (const float*)d_in[7];
    float* out = (float*)d_out;

    float* part = (float*)d_ws;   // part[32][B_SZ], 4MB

    nam_main<<<dim3(2048), dim3(256), 0, stream>>>(
        x, w1, b1, b2, w3, b3, w2, part);
    nam_final<<<dim3(B_SZ / 256), dim3(256), 0, stream>>>(part, bias, out);
}

// Round 24
// 125.187 us; speedup vs baseline: 1.0196x; 1.0089x over previous
//
#include <hip/hip_runtime.h>
#include <hip/hip_bf16.h>

// NAM_89739046683406: per-feature tiny MLP (B=32768, F=128, H=64)
// logit(b) = bias + sum_f [ relu(relu(x[b,f]*w1[f]+b1[f]) @ w2[f] + b2[f]) . w3[f] + b3[f] ]
// out = [1-sigmoid, sigmoid]
//
// R24 = R21 verbatim — the session best (123.9us total, main 62us), locked in
// after the three remaining levers each failed in isolation:
//   - R22 (packed math, -128 instr/chunk): VALUBusy 76->61% but time UP
//     -> not issue-bound at this occupancy.
//   - R23 (butterfly -> LDS quad-slices): neutral; latency relocated to the
//     epilogue + 524K bank conflicts (520 mod 32 = 8 aliasing).
//   - occupancy: LB(256,4) demotes registers to scratch (R13-R15) ->
//     3 blocks/CU is a hard ceiling for this body.
// Structure: one fused main kernel (wave = 1 feature x 512 rows, 8 chunks;
// w2 packed to MFMA A-fragments in a register preamble; b2 as MFMA C operand;
// x gather+shfl with software prefetch; per-chunk quad butterfly; LDS block
// reduce; plain sole-writer stores to part[32][B]) + final sigmoid kernel.
//
// Hard-won toolchain constraints (violation = FETCH/WRITE blowup at low
// VGPR_Count = scratch demotion, 2-3x slowdown):
//   - LB must be (256,3); (256,4) demotes.
//   - NO arrays of float2v with __builtin_elementwise_* math.
//   - Judge spills by FETCH/WRITE counters, not VGPR_Count.

#define B_SZ 32768
#define F_SZ 128
#define H_SZ 64

typedef short short8 __attribute__((ext_vector_type(8)));   // bf16 x8
typedef float floatx4 __attribute__((ext_vector_type(4)));  // fp32 x4 acc

// round-half-up bf16 pair-pack (proven form)
__device__ __forceinline__ unsigned pkbf(float lo, float hi) {
    unsigned ua = __float_as_uint(lo) + 0x8000u;
    unsigned ub = __float_as_uint(hi) + 0x8000u;
    return (ua >> 16) | (ub & 0xFFFF0000u);
}

// ---- main: block = 4 waves; wave wv owns feature f = (bx>>6)*4+wv,
//      rows [rg*512, rg*512+512), rg = bx&63. 8 chunks of 64 rows.
//      Preamble packs w2[f] -> A-fragments in registers (no prep kernel).
//      Output: part[gf][rb..rb+512) plain store (sole writer).
__global__ __launch_bounds__(256, 3)
void nam_main(const float* __restrict__ x,
              const float* __restrict__ w1, const float* __restrict__ b1,
              const float* __restrict__ b2, const float* __restrict__ w3,
              const float* __restrict__ b3,
              const float* __restrict__ w2,
              float* __restrict__ part)
{
    __shared__ float partial[4][512];    // 8KB

    const int tid  = threadIdx.x;
    const int lane = tid & 63;
    const int wv   = tid >> 6;           // 0..3
    const int l15  = lane & 15;
    const int quad = lane >> 4;
    const int rg   = blockIdx.x & 63;
    const int gf   = blockIdx.x >> 6;    // 0..31
    const int f    = gf * 4 + wv;
    const int rb   = rg * 512;

    // ---- per-wave resident tables ----
    // w2 A-fragments packed in-place from fp32 source:
    // frag (gt,ks): elem j = w2[f][k=ks*32+quad*8+j][g=gt*16+l15]
    const float* w2f = w2 + (size_t)f * H_SZ * H_SZ;
    short8 wfrag[4][2];
    #pragma unroll
    for (int gt = 0; gt < 4; ++gt)
        #pragma unroll
        for (int ks = 0; ks < 2; ++ks) {
            const float* src = w2f + (ks * 32 + quad * 8) * H_SZ + gt * 16 + l15;
            union { short8 s8; unsigned u[4]; } o;
            #pragma unroll
            for (int t = 0; t < 4; ++t)
                o.u[t] = pkbf(src[(2 * t) * H_SZ], src[(2 * t + 1) * H_SZ]);
            wfrag[gt][ks] = o.s8;
        }

    // w1/b1 fp32: element k = ks*32 + quad*8 + j
    float wk[2][8], bk[2][8];
    #pragma unroll
    for (int ks = 0; ks < 2; ++ks) {
        const float4* wq = (const float4*)(w1 + f * 64 + ks * 32 + quad * 8);
        const float4* bq = (const float4*)(b1 + f * 64 + ks * 32 + quad * 8);
        *(float4*)&wk[ks][0] = wq[0]; *(float4*)&wk[ks][4] = wq[1];
        *(float4*)&bk[ks][0] = bq[0]; *(float4*)&bk[ks][4] = bq[1];
    }

    // b2 as MFMA C operand quads; w3 scalar: element g = gt*16 + quad*4 + i
    floatx4 b2c[4];
    float w3f[4][4];
    #pragma unroll
    for (int gt = 0; gt < 4; ++gt) {
        float4 bv  = *(const float4*)(b2 + f * 64 + gt * 16 + quad * 4);
        float4 wv3 = *(const float4*)(w3 + f * 64 + gt * 16 + quad * 4);
        b2c[gt] = floatx4{bv.x, bv.y, bv.z, bv.w};
        w3f[gt][0] = wv3.x; w3f[gt][1] = wv3.y;
        w3f[gt][2] = wv3.z; w3f[gt][3] = wv3.w;
    }
    const float b3f = b3[f];

    // ---- 8 chunks of 64 rows, software-pipelined x gather ----
    float xv = x[(size_t)(rb + lane) * F_SZ + f];   // chunk 0

    #pragma unroll 1
    for (int c = 0; c < 8; ++c) {
        float xvn;
        if (c < 7)
            xvn = x[(size_t)(rb + (c + 1) * 64 + lane) * F_SZ + f];

        float xf[4];
        #pragma unroll
        for (int bt = 0; bt < 4; ++bt)
            xf[bt] = __shfl(xv, bt * 16 + l15, 64);

        // h1 B-fragments: B[k=quad*8+j][n=bt*16+l15]
        short8 hfrag[4][2];
        #pragma unroll
        for (int ks = 0; ks < 2; ++ks)
            #pragma unroll
            for (int bt = 0; bt < 4; ++bt) {
                union { short8 s8; __hip_bfloat162 h2[4]; } o;
                #pragma unroll
                for (int t = 0; t < 4; ++t) {
                    float h0 = fmaxf(fmaf(xf[bt], wk[ks][2 * t],     bk[ks][2 * t]),     0.0f);
                    float h1 = fmaxf(fmaf(xf[bt], wk[ks][2 * t + 1], bk[ks][2 * t + 1]), 0.0f);
                    o.h2[t] = __float22bfloat162_rn(make_float2(h0, h1));
                }
                hfrag[bt][ks] = o.s8;
            }

        // MFMA (C = b2c direct, D != C) + epilogue
        // D layout: g = gt*16 + quad*4 + i, n = bt*16 + l15
        float t[4] = {0.0f, 0.0f, 0.0f, 0.0f};
        #pragma unroll
        for (int gt = 0; gt < 4; ++gt)
            #pragma unroll
            for (int bt = 0; bt < 4; ++bt) {
                floatx4 acc = __builtin_amdgcn_mfma_f32_16x16x32_bf16(
                    wfrag[gt][0], hfrag[bt][0], b2c[gt], 0, 0, 0);
                acc = __builtin_amdgcn_mfma_f32_16x16x32_bf16(
                    wfrag[gt][1], hfrag[bt][1], acc, 0, 0, 0);
                #pragma unroll
                for (int i = 0; i < 4; ++i)
                    t[bt] = fmaf(fmaxf(acc[i], 0.0f), w3f[gt][i], t[bt]);
            }

        // quad-reduce (row = bt*16 + l15), publish per-chunk rows
        #pragma unroll
        for (int bt = 0; bt < 4; ++bt) {
            t[bt] += __shfl_xor(t[bt], 16, 64);
            t[bt] += __shfl_xor(t[bt], 32, 64);
        }
        if (quad == 0) {
            #pragma unroll
            for (int bt = 0; bt < 4; ++bt)
                partial[wv][c * 64 + bt * 16 + l15] = t[bt] + b3f;
        }

        xv = xvn;
    }

    __syncthreads();

    // block reduce over the 4 features -> plain coalesced store (sole writer)
    #pragma unroll
    for (int k = 0; k < 2; ++k) {
        int row = k * 256 + tid;
        float p = partial[0][row] + partial[1][row]
                + partial[2][row] + partial[3][row];
        part[(size_t)gf * B_SZ + rb + row] = p;
    }
}

// ---- final: 1 row/thread, sum 32 gf-partials + bias + sigmoid ----
__global__ __launch_bounds__(256)
void nam_final(const float* __restrict__ part, const float* __restrict__ bias,
               float* __restrict__ out)
{
    int b = blockIdx.x * 256 + threadIdx.x;
    float s = bias[0];
    #pragma unroll
    for (int gf = 0; gf < 32; ++gf)
        s += part[(size_t)gf * B_SZ + b];
    float p = 1.0f / (1.0f + __expf(-s));
    ((float2*)out)[b] = make_float2(1.0f - p, p);
}

extern "C" void kernel_launch(void* const* d_in, const int* in_sizes, int n_in,
                              void* d_out, int out_size, void* d_ws, size_t ws_size,
                              hipStream_t stream)
{
    const float* x    = (const float*)d_in[0];
    const float* w1   = (const float*)d_in[1];
    const float* b1   = (const float*)d_in[2];
    const float* w2   = (const float*)d_in[3];
    const float* b2   = (const float*)d_in[4];
    const float* w3   = (const float*)d_in[5];
    const float* b3   = (const float*)d_in[6];
    const float* bias = (const float*)d_in[7];
    float* out = (float*)d_out;

    float* part = (float*)d_ws;   // part[32][B_SZ], 4MB

    nam_main<<<dim3(2048), dim3(256), 0, stream>>>(
        x, w1, b1, b2, w3, b3, w2, part);
    nam_final<<<dim3(B_SZ / 256), dim3(256), 0, stream>>>(part, bias, out);
}